// Round 1
// baseline (671.545 us; speedup 1.0000x reference)
//
#include <hip/hip_runtime.h>

// FastVCompressor: VQ nearest-code + gather + sparsity mask.
//   keys   [4,4096,1024] f32
//   values [4,4096,1024] f32
//   codebook [256,1024]  f32
// out = concat(keys_c, values_c) f32, each [4,4096,1024]
//
// Round 0: correctness-first fp32 tiled GEMM-argmin.
//   Kernel A: per-code squared norm + codebook transpose (k-major) into ws.
//   Kernel B: 64-row x 256-code x K=1024 fp32 dot tile, per-row argmin of
//             (c_sq - 2*dot)  (drops row-constant ||x||^2; argmin identical).
//   Kernel C: gather codebook[idx] with (c_sq > 0.01) mask, coalesced f4.

#define H 1024
#define C 256
#define MT 64   // rows per block in argmin kernel
#define KC 32   // K chunk staged in LDS

__global__ __launch_bounds__(256) void prep_kernel(const float* __restrict__ cb,
                                                   float* __restrict__ c_sq,
                                                   float* __restrict__ wt) {
    const int b = blockIdx.x;   // code index
    const int t = threadIdx.x;  // 256 threads, one float4 each (H/4 = 256)
    const float4 v = *(const float4*)(cb + (size_t)b * H + 4 * t);
    // transpose: wt[k][code], k-major so GEMM staging is contiguous
    wt[(size_t)(4 * t + 0) * C + b] = v.x;
    wt[(size_t)(4 * t + 1) * C + b] = v.y;
    wt[(size_t)(4 * t + 2) * C + b] = v.z;
    wt[(size_t)(4 * t + 3) * C + b] = v.w;
    float s = v.x * v.x + v.y * v.y + v.z * v.z + v.w * v.w;
    #pragma unroll
    for (int off = 32; off > 0; off >>= 1) s += __shfl_down(s, off);
    __shared__ float red[4];
    if ((t & 63) == 0) red[t >> 6] = s;
    __syncthreads();
    if (t == 0) c_sq[b] = red[0] + red[1] + red[2] + red[3];
}

__global__ __launch_bounds__(256) void argmin_kernel(
    const float* __restrict__ keys, const float* __restrict__ vals,
    const float* __restrict__ wt, const float* __restrict__ c_sq,
    int* __restrict__ out_idx) {
    __shared__ float xs[KC][MT];   // 8 KB, k-major X tile
    __shared__ float wsm[KC][C];   // 32 KB, k-major W tile (also reused for argmin reduce)

    const int t = threadIdx.x;
    const float* __restrict__ X = blockIdx.y ? vals : keys;
    const int row0 = blockIdx.x * MT;
    const int cg = t & 31;        // code group: 8 codes each
    const int rg = t >> 5;        // row group: 8 rows each
    const int c0 = cg * 8;
    const int r0 = rg * 8;

    float acc[8][8];
    #pragma unroll
    for (int i = 0; i < 8; ++i)
        #pragma unroll
        for (int j = 0; j < 8; ++j) acc[i][j] = 0.0f;

    for (int kc = 0; kc < H; kc += KC) {
        __syncthreads();
        // stage X tile: 64 rows x 32 ks = 512 float4, 2 per thread (transpose to k-major)
        #pragma unroll
        for (int j = 0; j < 2; ++j) {
            const int i = t * 2 + j;
            const int row = i >> 3;
            const int kq = i & 7;
            const float4 v = *(const float4*)(X + (size_t)(row0 + row) * H + kc + kq * 4);
            xs[kq * 4 + 0][row] = v.x;
            xs[kq * 4 + 1][row] = v.y;
            xs[kq * 4 + 2][row] = v.z;
            xs[kq * 4 + 3][row] = v.w;
        }
        // stage W tile: 32 ks x 256 codes = 2048 float4, 8 per thread, already k-major
        #pragma unroll
        for (int j = 0; j < 8; ++j) {
            const int i = j * 256 + t;
            const int k = i >> 6;
            const int cq = (i & 63) * 4;
            const float4 v = *(const float4*)(wt + (size_t)(kc + k) * C + cq);
            *(float4*)&wsm[k][cq] = v;
        }
        __syncthreads();
        #pragma unroll
        for (int k = 0; k < KC; ++k) {
            float xv[8], wv[8];
            *(float4*)&xv[0] = *(const float4*)&xs[k][r0];
            *(float4*)&xv[4] = *(const float4*)&xs[k][r0 + 4];
            *(float4*)&wv[0] = *(const float4*)&wsm[k][c0];
            *(float4*)&wv[4] = *(const float4*)&wsm[k][c0 + 4];
            #pragma unroll
            for (int i = 0; i < 8; ++i)
                #pragma unroll
                for (int j = 0; j < 8; ++j) acc[i][j] = fmaf(xv[i], wv[j], acc[i][j]);
        }
    }

    float csq[8];
    *(float4*)&csq[0] = *(const float4*)(c_sq + c0);
    *(float4*)&csq[4] = *(const float4*)(c_sq + c0 + 4);

    __syncthreads();  // done reading wsm; reuse as reduction scratch
    float* redv = (float*)wsm;                              // [MT][32] values (8 KB)
    int* redi = (int*)((char*)wsm + MT * 32 * sizeof(float)); // [MT][32] indices (8 KB)

    #pragma unroll
    for (int i = 0; i < 8; ++i) {
        float bv = csq[0] - 2.0f * acc[i][0];
        int bi = c0;
        #pragma unroll
        for (int j = 1; j < 8; ++j) {
            const float v = csq[j] - 2.0f * acc[i][j];
            if (v < bv) { bv = v; bi = c0 + j; }   // strict <: first-occurrence argmin
        }
        redv[(r0 + i) * 32 + cg] = bv;
        redi[(r0 + i) * 32 + cg] = bi;
    }
    __syncthreads();
    if (t < MT) {
        float bv = redv[t * 32];
        int bi = redi[t * 32];
        for (int g = 1; g < 32; ++g) {            // ascending cg = ascending code order
            const float v = redv[t * 32 + g];
            if (v < bv) { bv = v; bi = redi[t * 32 + g]; }
        }
        out_idx[(size_t)blockIdx.y * (gridDim.x * MT) + row0 + t] = bi;
    }
}

__global__ __launch_bounds__(256) void gather_kernel(
    const float* __restrict__ cb, const float* __restrict__ c_sq,
    const int* __restrict__ idx, float* __restrict__ out) {
    const int row = blockIdx.x;
    const int t = threadIdx.x;
    const int ci = idx[row];
    const float m = (c_sq[ci] > 0.01f) ? 1.0f : 0.0f;  // ||c|| > 0.1  <=>  ||c||^2 > 0.01
    float4 v = *(const float4*)(cb + (size_t)ci * H + 4 * t);
    v.x *= m; v.y *= m; v.z *= m; v.w *= m;
    *(float4*)(out + (size_t)row * H + 4 * t) = v;
}

extern "C" void kernel_launch(void* const* d_in, const int* in_sizes, int n_in,
                              void* d_out, int out_size, void* d_ws, size_t ws_size,
                              hipStream_t stream) {
    const float* keys = (const float*)d_in[0];
    const float* vals = (const float*)d_in[1];
    const float* cb   = (const float*)d_in[2];
    float* out = (float*)d_out;

    // ws layout: c_sq[256] | wt[1024*256] | idx[32768]  (~1.2 MB)
    float* c_sq = (float*)d_ws;
    float* wt   = c_sq + C;
    int*   idx  = (int*)(wt + (size_t)H * C);

    const int rows = in_sizes[0] / H;  // 16384 per tensor

    prep_kernel<<<C, 256, 0, stream>>>(cb, c_sq, wt);
    dim3 gB(rows / MT, 2);
    argmin_kernel<<<gB, 256, 0, stream>>>(keys, vals, wt, c_sq, idx);
    gather_kernel<<<rows * 2, 256, 0, stream>>>(cb, c_sq, idx, out);
}

// Round 2
// 500.050 us; speedup vs baseline: 1.3430x; 1.3430x over previous
//
#include <hip/hip_runtime.h>

// FastVCompressor: VQ nearest-code + gather + sparsity mask.
//   keys   [4,4096,1024] f32, values [4,4096,1024] f32, codebook [256,1024] f32
// out = concat(keys_c, values_c) f32.
//
// R2: fp32 GEMM-argmin, conflict-free LDS layout.
//   - per-thread tile 8 rows x 8 codes; codes split {4cg..4cg+3} u {128+4cg..}
//     so wv reads are consecutive-float4 ds_read_b128 (conflict-free);
//     xv reads are same-address broadcasts within each half-wave (free).
//   - register prefetch of next K-chunk across the barrier.
//   - shfl-xor butterfly argmin across the 32 code-threads of each row group.

#define H 1024
#define C 256
#define MT 64   // rows per block
#define KC 32   // K chunk staged in LDS

__global__ __launch_bounds__(256) void prep_kernel(const float* __restrict__ cb,
                                                   float* __restrict__ c_sq,
                                                   float* __restrict__ wt) {
    const int b = blockIdx.x;   // code index
    const int t = threadIdx.x;  // 256 threads, one float4 each (H/4 = 256)
    const float4 v = *(const float4*)(cb + (size_t)b * H + 4 * t);
    // transpose: wt[k][code], k-major so GEMM staging is contiguous
    wt[(size_t)(4 * t + 0) * C + b] = v.x;
    wt[(size_t)(4 * t + 1) * C + b] = v.y;
    wt[(size_t)(4 * t + 2) * C + b] = v.z;
    wt[(size_t)(4 * t + 3) * C + b] = v.w;
    float s = v.x * v.x + v.y * v.y + v.z * v.z + v.w * v.w;
    #pragma unroll
    for (int off = 32; off > 0; off >>= 1) s += __shfl_down(s, off);
    __shared__ float red[4];
    if ((t & 63) == 0) red[t >> 6] = s;
    __syncthreads();
    if (t == 0) c_sq[b] = red[0] + red[1] + red[2] + red[3];
}

__global__ __launch_bounds__(256) void argmin_kernel(
    const float* __restrict__ keys, const float* __restrict__ vals,
    const float* __restrict__ wt, const float* __restrict__ c_sq,
    int* __restrict__ out_idx) {
    __shared__ float xs[KC][MT];   // 8 KB, k-major X tile
    __shared__ float wsm[KC][C];   // 32 KB, k-major W tile

    const int t = threadIdx.x;
    const float* __restrict__ X = blockIdx.y ? vals : keys;
    const int row0 = blockIdx.x * MT;
    const int cg = t & 31;        // code thread within row group
    const int rg = t >> 5;        // row group: 8 rows each (uniform per half-wave)
    const int c0a = cg * 4;       // codes c0a..c0a+3
    const int c0b = 128 + cg * 4; // codes c0b..c0b+3
    const int r0 = rg * 8;

    // staging index precompute
    const int xrow0 = (t * 2) >> 3;      // row of first X float4
    const int xkq0 = (t * 2) & 7;        // k-quad of first X float4
    const int xrow1 = (t * 2 + 1) >> 3;
    const int xkq1 = (t * 2 + 1) & 7;

    float acc[8][8];
    #pragma unroll
    for (int i = 0; i < 8; ++i)
        #pragma unroll
        for (int j = 0; j < 8; ++j) acc[i][j] = 0.0f;

    // prefetch chunk 0 into registers
    float4 xbuf0 = *(const float4*)(X + (size_t)(row0 + xrow0) * H + xkq0 * 4);
    float4 xbuf1 = *(const float4*)(X + (size_t)(row0 + xrow1) * H + xkq1 * 4);
    float4 wbuf[8];
    #pragma unroll
    for (int j = 0; j < 8; ++j) {
        const int i = j * 256 + t;
        wbuf[j] = *(const float4*)(wt + (size_t)(i >> 6) * C + (i & 63) * 4);
    }

    for (int kc = 0; kc < H; kc += KC) {
        __syncthreads();   // previous compute done reading LDS (no-op first iter)
        // write prefetched regs -> LDS
        xs[xkq0 * 4 + 0][xrow0] = xbuf0.x;
        xs[xkq0 * 4 + 1][xrow0] = xbuf0.y;
        xs[xkq0 * 4 + 2][xrow0] = xbuf0.z;
        xs[xkq0 * 4 + 3][xrow0] = xbuf0.w;
        xs[xkq1 * 4 + 0][xrow1] = xbuf1.x;
        xs[xkq1 * 4 + 1][xrow1] = xbuf1.y;
        xs[xkq1 * 4 + 2][xrow1] = xbuf1.z;
        xs[xkq1 * 4 + 3][xrow1] = xbuf1.w;
        #pragma unroll
        for (int j = 0; j < 8; ++j) {
            const int i = j * 256 + t;
            *(float4*)&wsm[i >> 6][(i & 63) * 4] = wbuf[j];
        }
        __syncthreads();
        // prefetch next chunk (consumed after compute; latency hidden)
        const int kn = kc + KC;
        if (kn < H) {
            xbuf0 = *(const float4*)(X + (size_t)(row0 + xrow0) * H + kn + xkq0 * 4);
            xbuf1 = *(const float4*)(X + (size_t)(row0 + xrow1) * H + kn + xkq1 * 4);
            #pragma unroll
            for (int j = 0; j < 8; ++j) {
                const int i = j * 256 + t;
                wbuf[j] = *(const float4*)(wt + (size_t)(kn + (i >> 6)) * C + (i & 63) * 4);
            }
        }
        #pragma unroll 4
        for (int k = 0; k < KC; ++k) {
            float xv[8], wv[8];
            *(float4*)&xv[0] = *(const float4*)&xs[k][r0];       // broadcast
            *(float4*)&xv[4] = *(const float4*)&xs[k][r0 + 4];   // broadcast
            *(float4*)&wv[0] = *(const float4*)&wsm[k][c0a];     // conflict-free
            *(float4*)&wv[4] = *(const float4*)&wsm[k][c0b];     // conflict-free
            #pragma unroll
            for (int i = 0; i < 8; ++i)
                #pragma unroll
                for (int j = 0; j < 8; ++j) acc[i][j] = fmaf(xv[i], wv[j], acc[i][j]);
        }
    }

    float csq[8];
    *(float4*)&csq[0] = *(const float4*)(c_sq + c0a);
    *(float4*)&csq[4] = *(const float4*)(c_sq + c0b);

    // per-row argmin: thread-local scan (ascending code order), then 32-lane
    // shfl-xor butterfly with explicit (==, smaller-index) tie-break.
    const size_t obase = (size_t)blockIdx.y * (gridDim.x * MT) + row0 + r0;
    #pragma unroll
    for (int i = 0; i < 8; ++i) {
        float bv = csq[0] - 2.0f * acc[i][0];
        int bi = c0a;
        #pragma unroll
        for (int j = 1; j < 8; ++j) {
            const float v = csq[j] - 2.0f * acc[i][j];
            const int ci = (j < 4) ? (c0a + j) : (c0b + j - 4);
            if (v < bv || (v == bv && ci < bi)) { bv = v; bi = ci; }
        }
        #pragma unroll
        for (int off = 1; off < 32; off <<= 1) {
            const float ov = __shfl_xor(bv, off);
            const int oi = __shfl_xor(bi, off);
            if (ov < bv || (ov == bv && oi < bi)) { bv = ov; bi = oi; }
        }
        if (cg == 0) out_idx[obase + i] = bi;
    }
}

__global__ __launch_bounds__(256) void gather_kernel(
    const float* __restrict__ cb, const float* __restrict__ c_sq,
    const int* __restrict__ idx, float* __restrict__ out) {
    const int t = threadIdx.x;
    const int row = blockIdx.x * 4 + (t >> 6);   // one row per wave
    const int lane = t & 63;
    const int ci = idx[row];
    const float m = (c_sq[ci] > 0.01f) ? 1.0f : 0.0f;  // ||c||>0.1 <=> ||c||^2>0.01
    const float4* __restrict__ src = (const float4*)(cb + (size_t)ci * H);
    float4* __restrict__ dst = (float4*)(out + (size_t)row * H);
    #pragma unroll
    for (int j = 0; j < 4; ++j) {
        float4 v = src[lane + 64 * j];
        v.x *= m; v.y *= m; v.z *= m; v.w *= m;
        dst[lane + 64 * j] = v;
    }
}

extern "C" void kernel_launch(void* const* d_in, const int* in_sizes, int n_in,
                              void* d_out, int out_size, void* d_ws, size_t ws_size,
                              hipStream_t stream) {
    const float* keys = (const float*)d_in[0];
    const float* vals = (const float*)d_in[1];
    const float* cb   = (const float*)d_in[2];
    float* out = (float*)d_out;

    // ws layout: c_sq[256] | wt[1024*256] | idx[32768]  (~1.2 MB)
    float* c_sq = (float*)d_ws;
    float* wt   = c_sq + C;
    int*   idx  = (int*)(wt + (size_t)H * C);

    const int rows = in_sizes[0] / H;  // 16384 per tensor

    prep_kernel<<<C, 256, 0, stream>>>(cb, c_sq, wt);
    dim3 gB(rows / MT, 2);
    argmin_kernel<<<gB, 256, 0, stream>>>(keys, vals, wt, c_sq, idx);
    gather_kernel<<<rows * 2 / 4, 256, 0, stream>>>(cb, c_sq, idx, out);
}

// Round 3
// 448.926 us; speedup vs baseline: 1.4959x; 1.1139x over previous
//
#include <hip/hip_runtime.h>

// FastVCompressor: VQ nearest-code + gather + sparsity mask.
//   keys [4,4096,1024] f32, values [4,4096,1024] f32, codebook [256,1024] f32
// out = concat(keys_c, values_c) f32.
//
// R3: fp32 GEMM-argmin, occupancy-oriented restructure.
//   - R2 was grid-limited: 512 blocks = 2 blocks/CU = 8 waves/CU, VALUBusy 40%.
//   - Now block = 128 rows x 64 codes, thread = 4 rows (lane-distinct, one
//     ds_read_b128, 2-way alias = free) x 8 codes (half-wave uniform ->
//     broadcast LDS reads). Grid = 128 x 4 codeblocks x 2 = 1024 blocks,
//     4 blocks/CU, 16 waves/CU.
//   - Codeblock split -> per-row partial (min, idx) pairs; combine fused into
//     the gather kernel (lexicographic min over 4 pairs keeps first-occurrence
//     tie semantics, since codeblock ranges are index-ascending).
//   - fmaf chain over k ascending: bit-identical dots to R2 (which passed
//     with absmax 0).

#define H 1024
#define C 256
#define MT 128  // rows per argmin block
#define CB 64   // codes per argmin block
#define KC 32   // K chunk staged in LDS

__global__ __launch_bounds__(256) void prep_kernel(const float* __restrict__ cb,
                                                   float* __restrict__ c_sq,
                                                   float* __restrict__ wt) {
    const int b = blockIdx.x;   // code index
    const int t = threadIdx.x;  // 256 threads, one float4 each (H/4 = 256)
    const float4 v = *(const float4*)(cb + (size_t)b * H + 4 * t);
    // transpose: wt[k][code], k-major so GEMM staging is contiguous
    wt[(size_t)(4 * t + 0) * C + b] = v.x;
    wt[(size_t)(4 * t + 1) * C + b] = v.y;
    wt[(size_t)(4 * t + 2) * C + b] = v.z;
    wt[(size_t)(4 * t + 3) * C + b] = v.w;
    float s = v.x * v.x + v.y * v.y + v.z * v.z + v.w * v.w;
    #pragma unroll
    for (int off = 32; off > 0; off >>= 1) s += __shfl_down(s, off);
    __shared__ float red[4];
    if ((t & 63) == 0) red[t >> 6] = s;
    __syncthreads();
    if (t == 0) c_sq[b] = red[0] + red[1] + red[2] + red[3];
}

__global__ __launch_bounds__(256, 4) void argmin_kernel(
    const float* __restrict__ keys, const float* __restrict__ vals,
    const float* __restrict__ wt, const float* __restrict__ c_sq,
    float2* __restrict__ partial) {
    __shared__ float xs[KC][MT];   // 16 KB, k-major X tile (reused for reduce)
    __shared__ float wsm[KC][CB];  // 8 KB, k-major W tile

    const int t = threadIdx.x;
    const float* __restrict__ X = blockIdx.z ? vals : keys;
    const int row0 = blockIdx.x * MT;
    const int cb0 = blockIdx.y * CB;
    const int rl = t & 31;        // row lane: rows rl*4 .. rl*4+3
    const int cg = t >> 5;        // code group (0..7): local codes cg*8..+7
    const int c0 = cg * 8;
    const int r0 = rl * 4;

    float acc[4][8];
    #pragma unroll
    for (int i = 0; i < 4; ++i)
        #pragma unroll
        for (int j = 0; j < 8; ++j) acc[i][j] = 0.0f;

    // prefetch chunk 0 into registers
    float4 xb[4], wb[2];
    #pragma unroll
    for (int j = 0; j < 4; ++j) {
        const int i = t + 256 * j;           // row = i>>3, kquad = i&7
        xb[j] = *(const float4*)(X + (size_t)(row0 + (i >> 3)) * H + (i & 7) * 4);
    }
    #pragma unroll
    for (int j = 0; j < 2; ++j) {
        const int i = t + 256 * j;           // k = i>>4, code4 = (i&15)*4
        wb[j] = *(const float4*)(wt + (size_t)(i >> 4) * C + cb0 + (i & 15) * 4);
    }

    for (int kc = 0; kc < H; kc += KC) {
        __syncthreads();   // previous compute done reading LDS (no-op first iter)
        #pragma unroll
        for (int j = 0; j < 4; ++j) {
            const int i = t + 256 * j;
            const int row = i >> 3, kq = i & 7;
            xs[kq * 4 + 0][row] = xb[j].x;
            xs[kq * 4 + 1][row] = xb[j].y;
            xs[kq * 4 + 2][row] = xb[j].z;
            xs[kq * 4 + 3][row] = xb[j].w;
        }
        #pragma unroll
        for (int j = 0; j < 2; ++j) {
            const int i = t + 256 * j;
            *(float4*)&wsm[i >> 4][(i & 15) * 4] = wb[j];
        }
        __syncthreads();
        // prefetch next chunk (consumed after compute; latency hidden)
        const int kn = kc + KC;
        if (kn < H) {
            #pragma unroll
            for (int j = 0; j < 4; ++j) {
                const int i = t + 256 * j;
                xb[j] = *(const float4*)(X + (size_t)(row0 + (i >> 3)) * H + kn + (i & 7) * 4);
            }
            #pragma unroll
            for (int j = 0; j < 2; ++j) {
                const int i = t + 256 * j;
                wb[j] = *(const float4*)(wt + (size_t)(kn + (i >> 4)) * C + cb0 + (i & 15) * 4);
            }
        }
        #pragma unroll 4
        for (int k = 0; k < KC; ++k) {
            float xv[4], wv[8];
            *(float4*)&xv[0] = *(const float4*)&xs[k][r0];      // lane-distinct b128
            *(float4*)&wv[0] = *(const float4*)&wsm[k][c0];     // half-wave broadcast
            *(float4*)&wv[4] = *(const float4*)&wsm[k][c0 + 4]; // half-wave broadcast
            #pragma unroll
            for (int i = 0; i < 4; ++i)
                #pragma unroll
                for (int j = 0; j < 8; ++j) acc[i][j] = fmaf(xv[i], wv[j], acc[i][j]);
        }
    }

    float csq[8];
    *(float4*)&csq[0] = *(const float4*)(c_sq + cb0 + c0);
    *(float4*)&csq[4] = *(const float4*)(c_sq + cb0 + c0 + 4);

    // per-row argmin within this 64-code block.
    // thread-local scan ascending code order -> LDS [cg][row] -> final scan.
    __syncthreads();  // done with xs/wsm
    float* redv = (float*)xs;                         // [8][MT] values (4 KB)
    int* redi = (int*)((char*)xs + 8 * MT * 4);       // [8][MT] indices (4 KB)

    #pragma unroll
    for (int i = 0; i < 4; ++i) {
        float bv = csq[0] - 2.0f * acc[i][0];
        int bi = c0;                                  // local code index
        #pragma unroll
        for (int j = 1; j < 8; ++j) {
            const float v = csq[j] - 2.0f * acc[i][j];
            if (v < bv) { bv = v; bi = c0 + j; }      // ascending: strict < = first
        }
        redv[cg * MT + r0 + i] = bv;
        redi[cg * MT + r0 + i] = bi;
    }
    __syncthreads();
    if (t < MT) {
        float bv = redv[t];
        int bi = redi[t];
        #pragma unroll
        for (int g = 1; g < 8; ++g) {                 // ascending cg = ascending code
            const float v = redv[g * MT + t];
            if (v < bv) { bv = v; bi = redi[g * MT + t]; }
        }
        const size_t row_g = (size_t)blockIdx.z * (gridDim.x * MT) + row0 + t;
        partial[row_g * 4 + blockIdx.y] = make_float2(bv, __int_as_float(cb0 + bi));
    }
}

__global__ __launch_bounds__(256) void combine_gather_kernel(
    const float* __restrict__ cb, const float* __restrict__ c_sq,
    const float2* __restrict__ partial, float* __restrict__ out) {
    const int t = threadIdx.x;
    const int row = blockIdx.x * 4 + (t >> 6);   // one wave per row
    const int lane = t & 63;
    // combine 4 codeblock partials (index-ascending blocks: strict < keeps
    // first occurrence; == needs smaller index -> lexicographic)
    float2 p = partial[(size_t)row * 4];
    float bv = p.x;
    int bi = __float_as_int(p.y);
    #pragma unroll
    for (int g = 1; g < 4; ++g) {
        p = partial[(size_t)row * 4 + g];
        const float v = p.x;
        const int i = __float_as_int(p.y);
        if (v < bv || (v == bv && i < bi)) { bv = v; bi = i; }
    }
    const float m = (c_sq[bi] > 0.01f) ? 1.0f : 0.0f;  // ||c||>0.1 <=> ||c||^2>0.01
    const float4* __restrict__ src = (const float4*)(cb + (size_t)bi * H);
    float4* __restrict__ dst = (float4*)(out + (size_t)row * H);
    #pragma unroll
    for (int j = 0; j < 4; ++j) {
        float4 v = src[lane + 64 * j];
        v.x *= m; v.y *= m; v.z *= m; v.w *= m;
        dst[lane + 64 * j] = v;
    }
}

extern "C" void kernel_launch(void* const* d_in, const int* in_sizes, int n_in,
                              void* d_out, int out_size, void* d_ws, size_t ws_size,
                              hipStream_t stream) {
    const float* keys = (const float*)d_in[0];
    const float* vals = (const float*)d_in[1];
    const float* cb   = (const float*)d_in[2];
    float* out = (float*)d_out;

    // ws layout: c_sq[256] | wt[1024*256] | partial[32768*4 float2]  (~2.1 MB)
    float* c_sq = (float*)d_ws;
    float* wt   = c_sq + C;
    float2* partial = (float2*)(wt + (size_t)H * C);

    const int rows = in_sizes[0] / H;  // 16384 per tensor

    prep_kernel<<<C, 256, 0, stream>>>(cb, c_sq, wt);
    dim3 gB(rows / MT, C / CB, 2);
    argmin_kernel<<<gB, 256, 0, stream>>>(keys, vals, wt, c_sq, partial);
    combine_gather_kernel<<<rows * 2 / 4, 256, 0, stream>>>(cb, c_sq, partial, out);
}